// Round 11
// baseline (78.129 us; speedup 1.0000x reference)
//
#include <hip/hip_runtime.h>
#include <stdint.h>

// Problem constants (128^3 grid, H=128, fixed by the reference instance)
#define NXC   128
#define NXY   16384      // 128*128
#define NTOT  2097152    // 128^3
#define NS    2048383    // 127^3
#define SXY   16129      // 127*127
#define SYC   127
#define LXY   15876      // 126*126
#define LTOT  2000376    // 126^3

// 2*log2(e): folded into W1,b1,W2,b2 so tanh needs no input scaling
#define SCALE 2.8853900817779268f

typedef __bf16 bf16x8 __attribute__((ext_vector_type(8)));
typedef float f32x4 __attribute__((ext_vector_type(4)));
typedef float f32x2 __attribute__((ext_vector_type(2)));

typedef const __attribute__((address_space(1))) uint32_t* gas_t;
typedef __attribute__((address_space(3))) uint32_t* las_t;

__device__ __forceinline__ float rcp_hw(float x) {
#if __has_builtin(__builtin_amdgcn_rcpf)
  return __builtin_amdgcn_rcpf(x);
#else
  return 1.0f / x;
#endif
}
__device__ __forceinline__ float exp2_hw(float x) {
#if __has_builtin(__builtin_amdgcn_exp2f)
  return __builtin_amdgcn_exp2f(x);
#else
  return __exp2f(x);
#endif
}

// Pair of tanh sharing ONE rcp (batched inversion; exact to ~2ulp):
// input z = 2*log2e*x; tanh(x) = 1 - 2/(2^z+1) = 1 - 2b/((2^za+1)(2^zb+1)) etc.
// min(z,15) guard: product <= (2^15+1)^2 ~ 1e9, no overflow; clamp err <= 6e-5.
__device__ __forceinline__ f32x2 tanh_pair(f32x2 z) {
  z.x = fminf(z.x, 15.0f);
  z.y = fminf(z.y, 15.0f);
  float a = exp2_hw(z.x) + 1.0f;
  float b = exp2_hw(z.y) + 1.0f;
  float r = rcp_hw(a * b);
  f32x2 n2;            // -2*b, -2*a  (packed mul)
  n2.x = -2.0f * b;
  n2.y = -2.0f * a;
  f32x2 out;
  out.x = fmaf(n2.x, r, 1.0f);   // 1 - 2/a
  out.y = fmaf(n2.y, r, 1.0f);   // 1 - 2/b
  return out;
}

// softplus(x) = max(x,0) + log1p(e^{-|x|})
__device__ __forceinline__ float softplus_f(float x) {
  float a = fabsf(x);
  return fmaxf(x, 0.0f) + __logf(1.0f + __expf(-a));
}

// DPP row_shr suffix-add: after stages 1,2,4,8 lane (row-local) 15 holds the
// 16-lane row sum. Pure VALU (no LDS traffic, ~2cy latency per stage).
template <int CTRL>
__device__ __forceinline__ float dpp_shr_add(float x) {
  int xi = __builtin_bit_cast(int, x);
  int sh = __builtin_amdgcn_update_dpp(0, xi, CTRL, 0xF, 0xF, true);
  return x + __builtin_bit_cast(float, sh);
}
__device__ __forceinline__ float row_suffix_sum16(float x) {
  x = dpp_shr_add<0x111>(x);   // row_shr:1
  x = dpp_shr_add<0x112>(x);   // row_shr:2
  x = dpp_shr_add<0x114>(x);   // row_shr:4
  x = dpp_shr_add<0x118>(x);   // row_shr:8
  return x;                    // lane cl==15 has the full sum
}

__device__ __forceinline__ void ld8v(const float* p, f32x2* o) {
  float4 a = *reinterpret_cast<const float4*>(p);
  float4 b = *reinterpret_cast<const float4*>(p + 4);
  o[0].x = a.x; o[0].y = a.y;
  o[1].x = a.z; o[1].y = a.w;
  o[2].x = b.x; o[2].y = b.y;
  o[3].x = b.z; o[3].y = b.w;
}

// Precompute LDS image: W2*SCALE -> bf16 transposed+XOR-swizzled;
// smallpre = [W1*SCALE | b1*SCALE | b2*SCALE | w3].
__global__ __launch_bounds__(256) void conv_kernel(
    const float* __restrict__ W1, const float* __restrict__ B1,
    const float* __restrict__ W2, const float* __restrict__ B2,
    const float* __restrict__ W3,
    __bf16* __restrict__ w2pre, float* __restrict__ smallpre)
{
  const int n = blockIdx.x * 256 + threadIdx.x;   // 2048 chunks = 16 c x 128 j
  if (n < 2048) {
    const int c = n >> 7, j = n & 127;
    bf16x8 v;
    #pragma unroll
    for (int e = 0; e < 8; ++e) v[e] = (__bf16)(SCALE * W2[(8 * c + e) * 128 + j]);
    *reinterpret_cast<bf16x8*>(&w2pre[(j << 7) + (((c ^ (j & 15)) & 15) << 3)]) = v;
  }
  if (blockIdx.x == 0) {
    for (int i = threadIdx.x; i < 768; i += 256) {
      float v;
      if (i < 384)      v = SCALE * W1[i];
      else if (i < 512) v = SCALE * B1[i - 384];
      else if (i < 640) v = SCALE * B2[i - 512];
      else              v = W3[i - 640];
      smallpre[i] = v;
    }
  }
}

// 512-thread blocks, one 64-point group per wave (r9 base structure).
// This round: paired-rcp tanh (trans 512->384/wave) + DPP suffix reductions
// (64 ds_swizzle/wave -> 0 LDS traffic).
__global__ __launch_bounds__(512) void mlp_kernel(
    const float* __restrict__ DATAX, const float* __restrict__ STAGX,
    const int* __restrict__ CI,
    const __bf16* __restrict__ w2pre, const float* __restrict__ smallpre,
    const float* __restrict__ B3, float* __restrict__ fout)
{
  __shared__ __align__(16) __bf16 w2t[16384];  // 32 KiB, pre-swizzled image
  __shared__ __align__(16) float smallb[768];  // W1 | b1 | b2 | w3 (pre-scaled)

  const int tid  = threadIdx.x;
  const int lane = tid & 63;
  const int wid  = tid >> 6;    // 0..7
  const int cl   = lane & 15;
  const int g    = lane >> 4;

  // ---- this wave's 64 points: decode + issue CI gather FIRST ----
  const int group = (blockIdx.x << 3) + wid;
  const int gbase = group << 6;
  const int p = gbase + lane;
  const unsigned bb = (unsigned)p / 17u;
  const int t = p - (int)bb * 17;
  const int ci = CI[bb];

  // ---- W2 + params staging: pure DMA (4KB per wave) ----
  {
    const char* gsrc = (const char*)w2pre + (wid << 12) + (lane << 4);
    char*       ldst = (char*)w2t + (wid << 12);
    #pragma unroll
    for (int i = 0; i < 4; ++i) {
      __builtin_amdgcn_global_load_lds(
          (gas_t)(const void*)(gsrc + (i << 10)),
          (las_t)(void*)(ldst + (i << 10)), 16, 0, 0);
    }
    if (wid == 7) {
      const char* gs = (const char*)smallpre + (lane << 4);
      char*       ld = (char*)smallb;
      #pragma unroll
      for (int i = 0; i < 3; ++i) {
        __builtin_amdgcn_global_load_lds(
            (gas_t)(const void*)(gs + (i << 10)),
            (las_t)(void*)(ld + (i << 10)), 16, 0, 0);
      }
    }
  }

  // ---- xyz gather (depends on ci; drains with the same vmcnt(0)) ----
  const int iz = ci >> 14, rem = ci & 16383, iy = rem >> 7, ix = rem & 127;
  const float* xp;
  if (t < 8) {                       // original corners, d in {-1,+1}
    int ox = ix + ((t & 4) ? 1 : -1);
    int oy = iy + ((t & 2) ? 1 : -1);
    int oz = iz + ((t & 1) ? 1 : -1);
    int fl = oz * NXY + oy * NXC + ox;
    fl = min(max(fl, 0), NTOT - 1);
    xp = DATAX + 3 * fl;
  } else if (t < 16) {               // staggered corners, d in {-1,0}
    int ts = t - 8;
    int sx = ix + ((ts & 4) ? 0 : -1);
    int sy = iy + ((ts & 2) ? 0 : -1);
    int sz = iz + ((ts & 1) ? 0 : -1);
    int fl = sx * SXY + sy * SYC + sz;
    fl = min(max(fl, 0), NS - 1);
    xp = STAGX + 3 * fl;
  } else {                           // pred point
    xp = DATAX + 3 * ci;
  }
  const float px = xp[0], py = xp[1], pz = xp[2];
  const float b3v = B3[0];

  __syncthreads();   // vmcnt(0) drain completes DMA + gathers

  const float* w1s = smallb;         // [384]  (SCALE*W1)
  const float* b1s = smallb + 384;   // [128]  (SCALE*b1)
  const float* b2s = smallb + 512;   // [128]  (SCALE*b2)
  const float* w3s = smallb + 640;   // [128]  (w3)

  // ---- broadcast xyz per m-tile row ----
  float rxv[4], ryv[4], rzv[4];
  #pragma unroll
  for (int mt = 0; mt < 4; ++mt) {
    int src = (mt << 4) + cl;
    rxv[mt] = __shfl(px, src);
    ryv[mt] = __shfl(py, src);
    rzv[mt] = __shfl(pz, src);
  }

  // ---- h1 = tanh(x@W1+b1) into A fragments, packed-f32 pairs ----
  bf16x8 A[4][4];   // [mt][kt]
  #pragma unroll
  for (int kt = 0; kt < 4; ++kt) {
    int k0 = (kt << 5) + (g << 3);
    f32x2 wx2[4], wy2[4], wz2[4], bv2[4];
    ld8v(&w1s[k0], wx2);
    ld8v(&w1s[128 + k0], wy2);
    ld8v(&w1s[256 + k0], wz2);
    ld8v(&b1s[k0], bv2);
    #pragma unroll
    for (int mt = 0; mt < 4; ++mt) {
      #pragma unroll
      for (int i = 0; i < 4; ++i) {
        f32x2 pre = rxv[mt] * wx2[i] + ryv[mt] * wy2[i]
                  + rzv[mt] * wz2[i] + bv2[i];     // packed fma chain
        f32x2 th = tanh_pair(pre);
        A[mt][kt][2 * i]     = (__bf16)th.x;
        A[mt][kt][2 * i + 1] = (__bf16)th.y;
      }
    }
  }

  // ---- layer2 MFMA (C seeded with SCALE*b2; W2 image pre-scaled) ----
  f32x2 s2[4][2];
  #pragma unroll
  for (int mt = 0; mt < 4; ++mt) {
    s2[mt][0] = 0.0f;
    s2[mt][1] = 0.0f;
  }

  #pragma unroll
  for (int nt = 0; nt < 8; ++nt) {
    const float b2v = b2s[cl + (nt << 4)];
    const float w3v = w3s[cl + (nt << 4)];
    f32x4 cc[4];
    #pragma unroll
    for (int mt = 0; mt < 4; ++mt) {
      f32x4 seed = {b2v, b2v, b2v, b2v};
      cc[mt] = seed;
    }
    const int row = (nt << 4) + cl;   // W2^T row = output neuron j
    #pragma unroll
    for (int kt = 0; kt < 4; ++kt) {
      int chunk = (kt << 2) + g;
      bf16x8 bfv = *reinterpret_cast<const bf16x8*>(
          &w2t[(row << 7) + ((chunk ^ cl) << 3)]);
      #pragma unroll
      for (int mt = 0; mt < 4; ++mt)
        cc[mt] = __builtin_amdgcn_mfma_f32_16x16x32_bf16(A[mt][kt], bfv, cc[mt], 0, 0, 0);
    }
    #pragma unroll
    for (int mt = 0; mt < 4; ++mt) {
      f32x2 lo, hi;
      lo.x = cc[mt][0]; lo.y = cc[mt][1];
      hi.x = cc[mt][2]; hi.y = cc[mt][3];
      s2[mt][0] += tanh_pair(lo) * w3v;   // packed fma
      s2[mt][1] += tanh_pair(hi) * w3v;
    }
  }

  // ---- layer3 reduce via DPP suffix-sum (lane cl==15 gets row total) ----
  #pragma unroll
  for (int mt = 0; mt < 4; ++mt) {
    float s0 = row_suffix_sum16(s2[mt][0].x);
    float s1 = row_suffix_sum16(s2[mt][0].y);
    float s2v = row_suffix_sum16(s2[mt][1].x);
    float s3 = row_suffix_sum16(s2[mt][1].y);
    if (cl == 15) {
      int base = gbase + (mt << 4) + (g << 2);
      float4 o;
      o.x = softplus_f(s0 + b3v);
      o.y = softplus_f(s1 + b3v);
      o.z = softplus_f(s2v + b3v);
      o.w = softplus_f(s3 + b3v);
      *reinterpret_cast<float4*>(&fout[base]) = o;
    }
  }
}

// Per-center laplacian loss terms + per-block partial sums.
__global__ __launch_bounds__(256) void reduce1(
    const float* __restrict__ f, const int* __restrict__ CI,
    const float* __restrict__ LAPLF, const float* __restrict__ DATAF,
    float* __restrict__ partials, int B)
{
  const int tid = threadIdx.x;
  const int b = blockIdx.x * 256 + tid;
  float sq = 0.f, mv = 0.f, ae = 0.f;
  if (b < B) {
    int ci = CI[b];
    int iz = ci >> 14, rem = ci & 16383, iy = rem >> 7, ix = rem & 127;
    bool valid = (ix >= 1) & (ix < 127) & (iy >= 1) & (iy < 127) &
                 (iz >= 1) & (iz < 127);
    const float* fb = f + b * 17;
    float fo[8], fs[8];
    #pragma unroll
    for (int i = 0; i < 8; ++i) { fo[i] = fb[i]; fs[i] = fb[8 + i]; }
    float pred = fb[16];
    const int ia[4] = {0, 2, 1, 3};
    const int ib[4] = {7, 5, 6, 4};
    float lap = 0.f;
    #pragma unroll
    for (int r = 0; r < 4; ++r) {
      float aa = fo[ia[r]] + fo[ib[r]];
      float bs = fs[ia[r]] + fs[ib[r]];
      lap += fabsf(aa - bs) / (aa + bs);   // IEEE div, matches reference
    }
    lap *= (1.0f / 2.25f);                 // / (3*delta), delta = 3*0.25
    int fl = (ix - 1) * LXY + (iy - 1) * 126 + (iz - 1);
    fl = min(max(fl, 0), LTOT - 1);
    float dlap = LAPLF[fl] - lap;
    if (valid) { sq = dlap * dlap; mv = 1.f; }
    ae = fabsf(pred - DATAF[ci]);
  }
  #pragma unroll
  for (int msk = 32; msk >= 1; msk >>= 1) {
    sq += __shfl_xor(sq, msk);
    mv += __shfl_xor(mv, msk);
    ae += __shfl_xor(ae, msk);
  }
  __shared__ float rs[3][4];
  int lane = tid & 63, wd = tid >> 6;
  if (lane == 0) { rs[0][wd] = sq; rs[1][wd] = mv; rs[2][wd] = ae; }
  __syncthreads();
  if (tid == 0) {
    partials[blockIdx.x * 3 + 0] = rs[0][0] + rs[0][1] + rs[0][2] + rs[0][3];
    partials[blockIdx.x * 3 + 1] = rs[1][0] + rs[1][1] + rs[1][2] + rs[1][3];
    partials[blockIdx.x * 3 + 2] = rs[2][0] + rs[2][1] + rs[2][2] + rs[2][3];
  }
}

__global__ __launch_bounds__(128) void reduce2(
    const float* __restrict__ partials, const float* __restrict__ lw,
    float* __restrict__ out, int np, float invB)
{
  const int t = threadIdx.x;
  float sq = 0.f, mv = 0.f, ae = 0.f;
  for (int i = t; i < np; i += 128) {
    sq += partials[3 * i + 0];
    mv += partials[3 * i + 1];
    ae += partials[3 * i + 2];
  }
  #pragma unroll
  for (int msk = 32; msk >= 1; msk >>= 1) {
    sq += __shfl_xor(sq, msk);
    mv += __shfl_xor(mv, msk);
    ae += __shfl_xor(ae, msk);
  }
  __shared__ float rs[3][2];
  int lane = t & 63, wd = t >> 6;
  if (lane == 0) { rs[0][wd] = sq; rs[1][wd] = mv; rs[2][wd] = ae; }
  __syncthreads();
  if (t == 0) {
    float S = rs[0][0] + rs[0][1];
    float M = rs[1][0] + rs[1][1];
    float A = rs[2][0] + rs[2][1];
    out[0] = lw[0] * (S / fmaxf(M, 1.0f)) + A * invB;
  }
}

extern "C" void kernel_launch(void* const* d_in, const int* in_sizes, int n_in,
                              void* d_out, int out_size, void* d_ws, size_t ws_size,
                              hipStream_t stream) {
  const float* DATAX = (const float*)d_in[0];
  const float* DATAF = (const float*)d_in[1];
  const float* STAGX = (const float*)d_in[2];
  const float* LAPLF = (const float*)d_in[3];
  const float* LW    = (const float*)d_in[4];
  const float* W1    = (const float*)d_in[5];
  const float* B1    = (const float*)d_in[6];
  const float* W2    = (const float*)d_in[7];
  const float* B2    = (const float*)d_in[8];
  const float* W3    = (const float*)d_in[9];
  const float* B3    = (const float*)d_in[10];
  const int*   CI    = (const int*)d_in[11];

  const int B = in_sizes[11];        // 32768
  const int P = 17 * B;              // 557056 MLP points (= 64 * 8704 exactly)
  const int ngroups = P >> 6;        // 8704
  const int nblocks = ngroups >> 3;  // 1088 blocks of 8 waves, 1 group/wave

  // d_ws layout: [w2pre 32KB][smallpre 3KB + pad][fbuf P floats][partials]
  __bf16* w2pre    = (__bf16*)d_ws;
  float*  smallpre = (float*)((char*)d_ws + 32768);
  float*  fbuf     = (float*)((char*)d_ws + 36864);
  float*  partials = fbuf + P;

  conv_kernel<<<8, 256, 0, stream>>>(W1, B1, W2, B2, W3, w2pre, smallpre);
  mlp_kernel<<<nblocks, 512, 0, stream>>>(DATAX, STAGX, CI, w2pre, smallpre,
                                          B3, fbuf);
  const int nb2 = (B + 255) >> 8;
  reduce1<<<nb2, 256, 0, stream>>>(fbuf, CI, LAPLF, DATAF, partials, B);
  reduce2<<<1, 128, 0, stream>>>(partials, LW, (float*)d_out, nb2, 1.0f / (float)B);
}

// Round 12
// 64.420 us; speedup vs baseline: 1.2128x; 1.2128x over previous
//
#include <hip/hip_runtime.h>
#include <stdint.h>

// Problem constants (128^3 grid, H=128, fixed by the reference instance)
#define NXC   128
#define NXY   16384      // 128*128
#define NTOT  2097152    // 128^3
#define NS    2048383    // 127^3
#define SXY   16129      // 127*127
#define SYC   127
#define LXY   15876      // 126*126
#define LTOT  2000376    // 126^3

// 2*log2(e): folded into W1,b1,W2,b2 so tanh needs no input scaling
#define SCALE 2.8853900817779268f

typedef __bf16 bf16x8 __attribute__((ext_vector_type(8)));
typedef float f32x4 __attribute__((ext_vector_type(4)));
typedef float f32x2 __attribute__((ext_vector_type(2)));

typedef const __attribute__((address_space(1))) uint32_t* gas_t;
typedef __attribute__((address_space(3))) uint32_t* las_t;

__device__ __forceinline__ float rcp_hw(float x) {
#if __has_builtin(__builtin_amdgcn_rcpf)
  return __builtin_amdgcn_rcpf(x);
#else
  return 1.0f / x;
#endif
}
__device__ __forceinline__ float exp2_hw(float x) {
#if __has_builtin(__builtin_amdgcn_exp2f)
  return __builtin_amdgcn_exp2f(x);
#else
  return __exp2f(x);
#endif
}

// input z = 2*log2e*x; returns tanh(x) = 1 - 2/(2^z + 1). Safe at +/-inf.
__device__ __forceinline__ f32x2 tanh_pre2(f32x2 z) {
  f32x2 e;
  e.x = exp2_hw(z.x);
  e.y = exp2_hw(z.y);
  f32x2 ep1 = e + 1.0f;
  f32x2 r;
  r.x = rcp_hw(ep1.x);
  r.y = rcp_hw(ep1.y);
  return 1.0f - 2.0f * r;   // contracts to packed fma
}

// softplus(x) = max(x,0) + log1p(e^{-|x|})
__device__ __forceinline__ float softplus_f(float x) {
  float a = fabsf(x);
  return fmaxf(x, 0.0f) + __logf(1.0f + __expf(-a));
}

__device__ __forceinline__ void ld8v(const float* p, f32x2* o) {
  float4 a = *reinterpret_cast<const float4*>(p);
  float4 b = *reinterpret_cast<const float4*>(p + 4);
  o[0].x = a.x; o[0].y = a.y;
  o[1].x = a.z; o[1].y = a.w;
  o[2].x = b.x; o[2].y = b.y;
  o[3].x = b.z; o[3].y = b.w;
}

// Precompute: W2*SCALE -> bf16 transposed+XOR-swizzled image;
// smallpre = [W1*S (384) | b1*S (128) | interleaved (b2*S, w3) pairs (256)].
__global__ __launch_bounds__(256) void conv_kernel(
    const float* __restrict__ W1, const float* __restrict__ B1,
    const float* __restrict__ W2, const float* __restrict__ B2,
    const float* __restrict__ W3,
    __bf16* __restrict__ w2pre, float* __restrict__ smallpre)
{
  const int n = blockIdx.x * 256 + threadIdx.x;   // 2048 chunks = 16 c x 128 j
  if (n < 2048) {
    const int c = n >> 7, j = n & 127;
    bf16x8 v;
    #pragma unroll
    for (int e = 0; e < 8; ++e) v[e] = (__bf16)(SCALE * W2[(8 * c + e) * 128 + j]);
    *reinterpret_cast<bf16x8*>(&w2pre[(j << 7) + (((c ^ (j & 15)) & 15) << 3)]) = v;
  }
  if (blockIdx.x == 0) {
    for (int i = threadIdx.x; i < 768; i += 256) {
      float v;
      if (i < 384)      v = SCALE * W1[i];
      else if (i < 512) v = SCALE * B1[i - 384];
      else {
        int q = (i - 512) >> 1;
        v = ((i & 1) == 0) ? (SCALE * B2[q]) : W3[q];
      }
      smallpre[i] = v;
    }
  }
}

// 256-thread blocks (best measured block-packing), LDS = EXACTLY 32 KiB (the
// W2 image only). Small params (3KB) come from global (L1-hot, shared by all
// blocks). One wave = one 64-point group. r9 math (packed f32, tanh_pre2).
__global__ __launch_bounds__(256) void mlp_kernel(
    const float* __restrict__ DATAX, const float* __restrict__ STAGX,
    const int* __restrict__ CI,
    const __bf16* __restrict__ w2pre, const float* __restrict__ smallpre,
    const float* __restrict__ B3, float* __restrict__ fout)
{
  __shared__ __align__(16) __bf16 w2t[16384];  // 32768 B exactly

  const int tid  = threadIdx.x;
  const int lane = tid & 63;
  const int wid  = tid >> 6;    // 0..3
  const int cl   = lane & 15;
  const int g    = lane >> 4;

  // ---- this wave's 64 points: decode + issue CI gather FIRST ----
  const int group = (blockIdx.x << 2) + wid;
  const int gbase = group << 6;
  const int p = gbase + lane;
  const unsigned bb = (unsigned)p / 17u;
  const int t = p - (int)bb * 17;
  const int ci = CI[bb];

  // ---- W2 staging: pure DMA (8KB per wave) ----
  {
    const char* gsrc = (const char*)w2pre + (wid << 13) + (lane << 4);
    char*       ldst = (char*)w2t + (wid << 13);
    #pragma unroll
    for (int i = 0; i < 8; ++i) {
      __builtin_amdgcn_global_load_lds(
          (gas_t)(const void*)(gsrc + (i << 10)),
          (las_t)(void*)(ldst + (i << 10)), 16, 0, 0);
    }
  }

  // ---- xyz gather (depends on ci; drains with the same vmcnt(0)) ----
  const int iz = ci >> 14, rem = ci & 16383, iy = rem >> 7, ix = rem & 127;
  const float* xp;
  if (t < 8) {                       // original corners, d in {-1,+1}
    int ox = ix + ((t & 4) ? 1 : -1);
    int oy = iy + ((t & 2) ? 1 : -1);
    int oz = iz + ((t & 1) ? 1 : -1);
    int fl = oz * NXY + oy * NXC + ox;
    fl = min(max(fl, 0), NTOT - 1);
    xp = DATAX + 3 * fl;
  } else if (t < 16) {               // staggered corners, d in {-1,0}
    int ts = t - 8;
    int sx = ix + ((ts & 4) ? 0 : -1);
    int sy = iy + ((ts & 2) ? 0 : -1);
    int sz = iz + ((ts & 1) ? 0 : -1);
    int fl = sx * SXY + sy * SYC + sz;
    fl = min(max(fl, 0), NS - 1);
    xp = STAGX + 3 * fl;
  } else {                           // pred point
    xp = DATAX + 3 * ci;
  }
  const float px = xp[0], py = xp[1], pz = xp[2];
  const float b3v = B3[0];

  // small params from global (L1-hot; identical across all blocks)
  const float* w1s = smallpre;         // [384]  (SCALE*W1)
  const float* b1s = smallpre + 384;   // [128]  (SCALE*b1)
  const float* bw  = smallpre + 512;   // [256]  (SCALE*b2, w3) pairs

  __syncthreads();   // vmcnt(0) drain completes DMA + gathers

  // ---- broadcast xyz per m-tile row ----
  float rxv[4], ryv[4], rzv[4];
  #pragma unroll
  for (int mt = 0; mt < 4; ++mt) {
    int src = (mt << 4) + cl;
    rxv[mt] = __shfl(px, src);
    ryv[mt] = __shfl(py, src);
    rzv[mt] = __shfl(pz, src);
  }

  // ---- h1 = tanh(x@W1+b1) into A fragments, packed-f32 pairs ----
  bf16x8 A[4][4];   // [mt][kt]
  #pragma unroll
  for (int kt = 0; kt < 4; ++kt) {
    int k0 = (kt << 5) + (g << 3);
    f32x2 wx2[4], wy2[4], wz2[4], bv2[4];
    ld8v(&w1s[k0], wx2);
    ld8v(&w1s[128 + k0], wy2);
    ld8v(&w1s[256 + k0], wz2);
    ld8v(&b1s[k0], bv2);
    #pragma unroll
    for (int mt = 0; mt < 4; ++mt) {
      #pragma unroll
      for (int i = 0; i < 4; ++i) {
        f32x2 pre = rxv[mt] * wx2[i] + ryv[mt] * wy2[i]
                  + rzv[mt] * wz2[i] + bv2[i];     // packed fma chain
        f32x2 th = tanh_pre2(pre);
        A[mt][kt][2 * i]     = (__bf16)th.x;
        A[mt][kt][2 * i + 1] = (__bf16)th.y;
      }
    }
  }

  // ---- layer2 MFMA (C seeded with SCALE*b2; W2 image pre-scaled) ----
  f32x2 s2[4][2];
  #pragma unroll
  for (int mt = 0; mt < 4; ++mt) {
    s2[mt][0] = 0.0f;
    s2[mt][1] = 0.0f;
  }

  #pragma unroll
  for (int nt = 0; nt < 8; ++nt) {
    const float2 bwv = *reinterpret_cast<const float2*>(&bw[(cl + (nt << 4)) << 1]);
    const float b2v = bwv.x, w3v = bwv.y;
    f32x4 cc[4];
    #pragma unroll
    for (int mt = 0; mt < 4; ++mt) {
      f32x4 seed = {b2v, b2v, b2v, b2v};
      cc[mt] = seed;
    }
    const int row = (nt << 4) + cl;   // W2^T row = output neuron j
    #pragma unroll
    for (int kt = 0; kt < 4; ++kt) {
      int chunk = (kt << 2) + g;
      bf16x8 bfv = *reinterpret_cast<const bf16x8*>(
          &w2t[(row << 7) + ((chunk ^ cl) << 3)]);
      #pragma unroll
      for (int mt = 0; mt < 4; ++mt)
        cc[mt] = __builtin_amdgcn_mfma_f32_16x16x32_bf16(A[mt][kt], bfv, cc[mt], 0, 0, 0);
    }
    #pragma unroll
    for (int mt = 0; mt < 4; ++mt) {
      f32x2 lo, hi;
      lo.x = cc[mt][0]; lo.y = cc[mt][1];
      hi.x = cc[mt][2]; hi.y = cc[mt][3];
      s2[mt][0] += tanh_pre2(lo) * w3v;   // packed fma
      s2[mt][1] += tanh_pre2(hi) * w3v;
    }
  }

  // ---- reduce layer3 across the 16 neuron-lanes, softplus, store ----
  float s[4][4];
  #pragma unroll
  for (int mt = 0; mt < 4; ++mt) {
    s[mt][0] = s2[mt][0].x; s[mt][1] = s2[mt][0].y;
    s[mt][2] = s2[mt][1].x; s[mt][3] = s2[mt][1].y;
    #pragma unroll
    for (int r = 0; r < 4; ++r) {
      float v = s[mt][r];
      v += __shfl_xor(v, 1);
      v += __shfl_xor(v, 2);
      v += __shfl_xor(v, 4);
      v += __shfl_xor(v, 8);
      s[mt][r] = v;
    }
  }
  if (cl == 0) {
    #pragma unroll
    for (int mt = 0; mt < 4; ++mt) {
      int base = gbase + (mt << 4) + (g << 2);
      float4 o;
      o.x = softplus_f(s[mt][0] + b3v);
      o.y = softplus_f(s[mt][1] + b3v);
      o.z = softplus_f(s[mt][2] + b3v);
      o.w = softplus_f(s[mt][3] + b3v);
      *reinterpret_cast<float4*>(&fout[base]) = o;
    }
  }
}

// Per-center laplacian loss terms + per-block partial sums.
__global__ __launch_bounds__(256) void reduce1(
    const float* __restrict__ f, const int* __restrict__ CI,
    const float* __restrict__ LAPLF, const float* __restrict__ DATAF,
    float* __restrict__ partials, int B)
{
  const int tid = threadIdx.x;
  const int b = blockIdx.x * 256 + tid;
  float sq = 0.f, mv = 0.f, ae = 0.f;
  if (b < B) {
    int ci = CI[b];
    int iz = ci >> 14, rem = ci & 16383, iy = rem >> 7, ix = rem & 127;
    bool valid = (ix >= 1) & (ix < 127) & (iy >= 1) & (iy < 127) &
                 (iz >= 1) & (iz < 127);
    const float* fb = f + b * 17;
    float fo[8], fs[8];
    #pragma unroll
    for (int i = 0; i < 8; ++i) { fo[i] = fb[i]; fs[i] = fb[8 + i]; }
    float pred = fb[16];
    const int ia[4] = {0, 2, 1, 3};
    const int ib[4] = {7, 5, 6, 4};
    float lap = 0.f;
    #pragma unroll
    for (int r = 0; r < 4; ++r) {
      float aa = fo[ia[r]] + fo[ib[r]];
      float bs = fs[ia[r]] + fs[ib[r]];
      lap += fabsf(aa - bs) / (aa + bs);   // IEEE div, matches reference
    }
    lap *= (1.0f / 2.25f);                 // / (3*delta), delta = 3*0.25
    int fl = (ix - 1) * LXY + (iy - 1) * 126 + (iz - 1);
    fl = min(max(fl, 0), LTOT - 1);
    float dlap = LAPLF[fl] - lap;
    if (valid) { sq = dlap * dlap; mv = 1.f; }
    ae = fabsf(pred - DATAF[ci]);
  }
  #pragma unroll
  for (int msk = 32; msk >= 1; msk >>= 1) {
    sq += __shfl_xor(sq, msk);
    mv += __shfl_xor(mv, msk);
    ae += __shfl_xor(ae, msk);
  }
  __shared__ float rs[3][4];
  int lane = tid & 63, wd = tid >> 6;
  if (lane == 0) { rs[0][wd] = sq; rs[1][wd] = mv; rs[2][wd] = ae; }
  __syncthreads();
  if (tid == 0) {
    partials[blockIdx.x * 3 + 0] = rs[0][0] + rs[0][1] + rs[0][2] + rs[0][3];
    partials[blockIdx.x * 3 + 1] = rs[1][0] + rs[1][1] + rs[1][2] + rs[1][3];
    partials[blockIdx.x * 3 + 2] = rs[2][0] + rs[2][1] + rs[2][2] + rs[2][3];
  }
}

__global__ __launch_bounds__(128) void reduce2(
    const float* __restrict__ partials, const float* __restrict__ lw,
    float* __restrict__ out, int np, float invB)
{
  const int t = threadIdx.x;
  float sq = 0.f, mv = 0.f, ae = 0.f;
  for (int i = t; i < np; i += 128) {
    sq += partials[3 * i + 0];
    mv += partials[3 * i + 1];
    ae += partials[3 * i + 2];
  }
  #pragma unroll
  for (int msk = 32; msk >= 1; msk >>= 1) {
    sq += __shfl_xor(sq, msk);
    mv += __shfl_xor(mv, msk);
    ae += __shfl_xor(ae, msk);
  }
  __shared__ float rs[3][2];
  int lane = t & 63, wd = t >> 6;
  if (lane == 0) { rs[0][wd] = sq; rs[1][wd] = mv; rs[2][wd] = ae; }
  __syncthreads();
  if (t == 0) {
    float S = rs[0][0] + rs[0][1];
    float M = rs[1][0] + rs[1][1];
    float A = rs[2][0] + rs[2][1];
    out[0] = lw[0] * (S / fmaxf(M, 1.0f)) + A * invB;
  }
}

extern "C" void kernel_launch(void* const* d_in, const int* in_sizes, int n_in,
                              void* d_out, int out_size, void* d_ws, size_t ws_size,
                              hipStream_t stream) {
  const float* DATAX = (const float*)d_in[0];
  const float* DATAF = (const float*)d_in[1];
  const float* STAGX = (const float*)d_in[2];
  const float* LAPLF = (const float*)d_in[3];
  const float* LW    = (const float*)d_in[4];
  const float* W1    = (const float*)d_in[5];
  const float* B1    = (const float*)d_in[6];
  const float* W2    = (const float*)d_in[7];
  const float* B2    = (const float*)d_in[8];
  const float* W3    = (const float*)d_in[9];
  const float* B3    = (const float*)d_in[10];
  const int*   CI    = (const int*)d_in[11];

  const int B = in_sizes[11];        // 32768
  const int P = 17 * B;              // 557056 MLP points (= 64 * 8704 exactly)
  const int ngroups = P >> 6;        // 8704
  const int nblocks = ngroups >> 2;  // 2176 blocks of 4 waves, 1 group/wave

  // d_ws layout: [w2pre 32KB][smallpre 3KB + pad][fbuf P floats][partials]
  __bf16* w2pre    = (__bf16*)d_ws;
  float*  smallpre = (float*)((char*)d_ws + 32768);
  float*  fbuf     = (float*)((char*)d_ws + 36864);
  float*  partials = fbuf + P;

  conv_kernel<<<8, 256, 0, stream>>>(W1, B1, W2, B2, W3, w2pre, smallpre);
  mlp_kernel<<<nblocks, 256, 0, stream>>>(DATAX, STAGX, CI, w2pre, smallpre,
                                          B3, fbuf);
  const int nb2 = (B + 255) >> 8;
  reduce1<<<nb2, 256, 0, stream>>>(fbuf, CI, LAPLF, DATAF, partials, B);
  reduce2<<<1, 128, 0, stream>>>(partials, LW, (float*)d_out, nb2, 1.0f / (float)B);
}